// Round 12
// baseline (1129347.754 us; speedup 1.0000x reference)
//
#include <hip/hip_runtime.h>
#include <math.h>

#define Bq   16
#define Tq   1024
#define OUTq 64
#define Hq   512
#define Nq   128
#define Mq   40
#define NT   512
#define NISL 16        // islands = batches
#define GWG  13        // gate WGs per island (12 x 40 dims + 1 x 32 dims)
#define IWG  14        // WGs per island (GWG + 1 mem)
#define NWG  224
#define EPSq 1e-8f
#define MAGIC 0x00C0FFEEu
#define MAGICL 0x5EC0FFEEDEADBEEFull

typedef unsigned long long ull;

__device__ __forceinline__ float sigmf(float x){ return 1.f/(1.f + expf(-x)); }
__device__ __forceinline__ float softplusf(float x){ return (x > 20.f) ? x : log1pf(expf(x)); }

// Agent-scope atomic ops: authoritative cross-XCD path (IC coherence point).
__device__ __forceinline__ ull icld64(const ull* p){
  return __hip_atomic_load(p, __ATOMIC_RELAXED, __HIP_MEMORY_SCOPE_AGENT);
}
__device__ __forceinline__ void icst64(ull* p, ull v){
  __hip_atomic_store(p, v, __ATOMIC_RELAXED, __HIP_MEMORY_SCOPE_AGENT);
}
// IC poll: sc0+sc1 bypasses L1 and L2 -> coherent with agent stores, coalescing.
__device__ __forceinline__ ull icpoll64(const ull* p){
  ull v;
  asm volatile("global_load_dwordx2 %0, %1, off sc0 sc1\n\ts_waitcnt vmcnt(0)"
               : "=v"(v) : "v"(p) : "memory");
  return v;
}
// Local poll: sc0 only = bypass L1, served by the XCD's L2 (or IC on L2 miss,
// which is also coherent for write-back lines). Coherent with SAME-XCD plain
// stores (write-through L1). Enabled only after the runtime mechanism test.
__device__ __forceinline__ ull l2ld64(const ull* p){
  ull v;
  asm volatile("global_load_dwordx2 %0, %1, off sc0\n\ts_waitcnt vmcnt(0)"
               : "=v"(v) : "v"(p) : "memory");
  return v;
}
__device__ __forceinline__ ull packtv(unsigned tag, float v){
  return ((ull)tag << 32) | (ull)__float_as_uint(v);
}
__device__ __forceinline__ float lowf(ull v){ return __uint_as_float((unsigned)v); }

// Dual publish: plain store (write-through to the producer's L2 — visible to
// same-XCD sc0 polls) + agent shadow (always correct). Tag+payload are one
// atomic 8B word; tags monotone; parity-2 reuse gated by the dependency chain.
__device__ __forceinline__ void publish(ull* loc, ull* sh, ull v){
  *loc = v;
  icst64(sh, v);
}
// mode 2: HW-verified co-XCD island -> bounded local L2 poll, then agent tail.
// mode 1: sc0sc1 IC poll (r4-proven). mode 0: agent atomic loop.
// Every mode ends in the agent loop -> no configuration can hang.
__device__ __forceinline__ float waitword(const ull* loc, const ull* sh,
                                          unsigned want, int mode){
  if (mode == 2){
    #pragma unroll 1
    for (int i = 0; i < 4096; ++i){
      const ull v = l2ld64(loc);
      if ((unsigned)(v >> 32) == want) return lowf(v);
      __builtin_amdgcn_s_sleep(1);
    }
  } else if (mode == 1){
    #pragma unroll 1
    for (int i = 0; i < 4096; ++i){
      const ull v = icpoll64(sh);
      if ((unsigned)(v >> 32) == want) return lowf(v);
      __builtin_amdgcn_s_sleep(1);
    }
  }
  #pragma unroll 1
  for (;;){
    const ull v = icld64(sh);
    if ((unsigned)(v >> 32) == want) return lowf(v);
    __builtin_amdgcn_s_sleep(1);
  }
}

extern "C" __global__ void __launch_bounds__(NT, 1)
ntm_kernel(const float* __restrict__ xg,  const float* __restrict__ h0g,
           const float* __restrict__ c0g, const float* __restrict__ mem0g,
           const float* __restrict__ read0g,
           const float* __restrict__ Wih, const float* __restrict__ bih,
           const float* __restrict__ Whh, const float* __restrict__ bhh,
           const float* __restrict__ Wfc, const float* __restrict__ bfc,
           const float* __restrict__ We,  const float* __restrict__ be,
           const float* __restrict__ Wa,  const float* __restrict__ ba,
           const float* __restrict__ Wk,  const float* __restrict__ bk,
           const float* __restrict__ Wb,  const float* __restrict__ bbeta,
           float* __restrict__ yout, ull* __restrict__ rdy,
           ull* __restrict__ h_sh, ull* __restrict__ r_sh,
           ull* __restrict__ h_loc, ull* __restrict__ r_loc,
           ull* __restrict__ xtab, ull* __restrict__ asg,
           ull* __restrict__ votes, ull* __restrict__ verd,
           ull* __restrict__ ltest)
{
  const int blk = blockIdx.x;
  const int tid = threadIdx.x;
  __shared__ __align__(16) char smem[41344];
  __shared__ int s_bat, s_slot, s_mode;
  ull* magic = rdy + 1;

  // ---------- one-time: XCD discovery, island assignment, mechanism test ----
  if (tid == 0){
    // publish this WG's physical XCD register value (grouping is by EQUALITY
    // of the raw register — correct even if the field layout differs)
    const unsigned xcc = (unsigned)__builtin_amdgcn_s_getreg(63508); // id20,off0,sz32
    icst64(&xtab[blk], (1ull << 24) | (ull)(xcc & 0xFFFFFFu));
    __hip_atomic_fetch_add(rdy, 1ull, __ATOMIC_RELAXED, __HIP_MEMORY_SCOPE_AGENT);
    while (icld64(rdy) < (ull)NWG) __builtin_amdgcn_s_sleep(8);
    if (blk == 0) icst64(magic, ((ull)MAGIC << 32) | 1ull);
    int fast = 0;
    #pragma unroll 1
    for (int i = 0; i < 4000; ++i){
      if ((unsigned)(icpoll64(magic) >> 32) == MAGIC){ fast = 1; break; }
      __builtin_amdgcn_s_sleep(2);
    }
    if (blk == 0){
      // group blocks by equal XCC value; carve islands of 14 co-XCD blocks
      int* xv    = (int*)smem;          // 224
      int* used  = xv   + NWG;          // 224
      int* list  = used + NWG;          // 224
      int* pool  = list + NWG;          // 224
      for (int b = 0; b < NWG; ++b){
        ull v;
        #pragma unroll 1
        do { v = icld64(&xtab[b]); if (!((v >> 24) & 1)) __builtin_amdgcn_s_sleep(2); }
        while (!((v >> 24) & 1));
        xv[b] = (int)(v & 0xFFFFFFu);
        used[b] = 0;
      }
      int isl = 0;
      for (int b0 = 0; b0 < NWG && isl < NISL; ++b0){
        if (used[b0]) continue;
        const int val = xv[b0];
        int c = 0;
        for (int b = b0; b < NWG; ++b)
          if (!used[b] && xv[b] == val) list[c++] = b;
        int taken = 0;
        while (c - taken >= IWG && isl < NISL){
          for (int s = 0; s < IWG; ++s){
            const int b = list[taken++];
            used[b] = 1;
            icst64(&asg[b], (1ull << 32) | ((ull)isl << 16) | ((ull)s << 8) | 1ull);
          }
          isl++;
        }
      }
      int pc = 0;
      for (int b = 0; b < NWG; ++b) if (!used[b]) pool[pc++] = b;
      while (isl < NISL){
        for (int s = 0; s < IWG; ++s){
          const int b = pool[--pc];
          icst64(&asg[b], (1ull << 32) | ((ull)isl << 16) | ((ull)s << 8) | 0ull);
        }
        isl++;
      }
    }
    ull av;
    #pragma unroll 1
    do { av = icld64(&asg[blk]); if (!(av >> 32)) __builtin_amdgcn_s_sleep(2); }
    while (!(av >> 32));
    const int bat  = (int)((av >> 16) & 0xFF);
    const int slot = (int)((av >> 8) & 0xFF);
    const int lcap = (int)(av & 1);
    int uselocal = 0;
    if (lcap){
      // mechanism test: slot0 PLAIN-stores; members must see it via sc0 poll
      if (slot == 0){
        ltest[bat*16] = MAGICL;
        asm volatile("s_waitcnt vmcnt(0)" ::: "memory");
      }
      int hit = 0;
      #pragma unroll 1
      for (int i = 0; i < 1500; ++i){
        if (l2ld64(&ltest[bat*16]) == MAGICL){ hit = 1; break; }
        __builtin_amdgcn_s_sleep(1);
      }
      icst64(&votes[bat*16 + slot], 0x100ull | (ull)hit);
      if (slot == 0){
        int all = 1;
        for (int s = 0; s < IWG; ++s){
          ull v;
          #pragma unroll 1
          do { v = icld64(&votes[bat*16 + s]); if (!(v & 0x100)) __builtin_amdgcn_s_sleep(2); }
          while (!(v & 0x100));
          all &= (int)(v & 1);
        }
        icst64(&verd[bat*16], 0x100ull | (ull)all);
      }
      ull v;
      #pragma unroll 1
      do { v = icld64(&verd[bat*16]); if (!(v & 0x100)) __builtin_amdgcn_s_sleep(2); }
      while (!(v & 0x100));
      uselocal = (int)(v & 1);
    }
    s_bat = bat; s_slot = slot;
    s_mode = uselocal ? 2 : (fast ? 1 : 0);
  }
  __syncthreads();
  const int bat = s_bat, slot = s_slot, mode = s_mode;

  if (slot < GWG){
    // ---- gate WG: island `bat`, h-dims [d0, d0+nd) (all 4 gates) ----
    float* inp_s  = (float*)smem;               // 640 f: x[0,64) h[64,576)
    float* red_s  = (float*)(smem + 2560);      // 160 x 17
    float* rw_s   = (float*)(smem + 13440);     // 160 x 41 (r-slice weights)
    float* r_s    = (float*)(smem + 39680);     // 40
    float* gate_s = (float*)(smem + 39840);     // 160
    float* c_s    = (float*)(smem + 40480);     // 40
    float* bias_s = (float*)(smem + 40640);     // 160

    const int kseg  = tid & 15;       // 36-float k-slice of 576 (x|h)
    const int rslot = tid >> 4;       // 32 row-slots x 5 rows (padded)
    const int nd    = (slot < 12) ? 40 : 32;
    const int d0    = slot * 40;
    const int rowsR = 4 * nd;         // 160 or 128 real rows

    float4 w4[5][9];
    #pragma unroll
    for (int rr = 0; rr < 5; ++rr){
      const int row = rslot*5 + rr;
      if (row < rowsR){
        const int gate = row / nd, ld = row - gate*nd;
        const int grow = gate*Hq + d0 + ld;
        #pragma unroll
        for (int kk = 0; kk < 9; ++kk){
          float v[4];
          #pragma unroll
          for (int c4 = 0; c4 < 4; ++c4){
            const int k = kseg*36 + kk*4 + c4;
            v[c4] = (k < 64) ? Wih[grow*104 + k] : Whh[grow*512 + (k - 64)];
          }
          w4[rr][kk] = make_float4(v[0], v[1], v[2], v[3]);
        }
      } else {
        #pragma unroll
        for (int kk = 0; kk < 9; ++kk) w4[rr][kk] = make_float4(0.f,0.f,0.f,0.f);
      }
    }
    if (tid < rowsR){
      const int gate = tid / nd, ld = tid - gate*nd;
      const int grow = gate*Hq + d0 + ld;
      bias_s[tid] = bih[grow] + bhh[grow];
    }
    for (int i = tid; i < rowsR*40; i += NT){
      const int row = i / 40, m = i - row*40;
      const int gate = row / nd, ld = row - gate*nd;
      const int grow = gate*Hq + d0 + ld;
      rw_s[row*41 + m] = Wih[grow*104 + 64 + m];
    }
    if (tid < nd) c_s[tid] = c0g[bat*Hq + d0 + tid];
    if (tid < 16)
      *(float4*)&inp_s[tid*4] = ((const float4*)xg)[(bat*Tq + 0)*16 + tid];
    if (tid < 128)
      *(float4*)&inp_s[64 + tid*4] = ((const float4*)h0g)[bat*128 + tid];
    __syncthreads();

    for (int t = 0; t < Tq; ++t){
      const int p = t & 1, pm = (t - 1) & 1;
      // main GEMV over x+h (576) — overlaps the island's mem phase
      float acc[5] = {0.f,0.f,0.f,0.f,0.f};
      {
        const float* bp = inp_s + kseg*36;
        #pragma unroll
        for (int kk = 0; kk < 9; ++kk){
          const float4 f = *(const float4*)&bp[kk*4];
          #pragma unroll
          for (int rr = 0; rr < 5; ++rr)
            acc[rr] += w4[rr][kk].x*f.x + w4[rr][kk].y*f.y
                     + w4[rr][kk].z*f.z + w4[rr][kk].w*f.w;
        }
      }
      #pragma unroll
      for (int rr = 0; rr < 5; ++rr)
        red_s[(rslot*5 + rr)*17 + kseg] = acc[rr];
      // r(t-1): island hop (t=0: pristine input)
      if (t == 0){
        if (tid < 40) r_s[tid] = read0g[bat*Mq + tid];
      } else if (tid < 40){
        const int idx = (pm*NISL + bat)*Mq + tid;
        r_s[tid] = waitword(&r_loc[idx], &r_sh[idx], (unsigned)t, mode);
      }
      __syncthreads();
      if (tid < rowsR){
        float s2 = bias_s[tid];
        const float* rp = &red_s[tid*17];
        #pragma unroll
        for (int q = 0; q < 16; ++q) s2 += rp[q];
        const float* rwp = &rw_s[tid*41];
        #pragma unroll
        for (int m = 0; m < 40; ++m) s2 += rwp[m]*r_s[m];
        gate_s[tid] = s2;
      }
      __syncthreads();
      if (tid < nd){
        const float gi = gate_s[tid];
        const float gf = gate_s[nd + tid];
        const float gc = gate_s[2*nd + tid];
        const float go = gate_s[3*nd + tid];
        const float iv = sigmf(gi), fv = sigmf(gf), gv = tanhf(gc), ov = sigmf(go);
        const float cn = fv*c_s[tid] + iv*gv;
        const float hn = ov*tanhf(cn);
        c_s[tid] = cn;
        const int idx = (p*NISL + bat)*Hq + d0 + tid;
        publish(&h_loc[idx], &h_sh[idx], packtv((unsigned)(t+1), hn));
        if (t == Tq - 1){
          yout[Bq*Tq*OUTq + bat*Hq + d0 + tid] = hn;             // final h
          yout[Bq*Tq*OUTq + Bq*Hq + bat*Hq + d0 + tid] = cn;     // final c
        }
      }
      // stage full h(t) for next GEMV: one dim per thread, island hop
      {
        const int idx = (p*NISL + bat)*Hq + tid;
        inp_s[64 + tid] = waitword(&h_loc[idx], &h_sh[idx], (unsigned)(t+1), mode);
      }
      if (t + 1 < Tq && tid < 16)
        *(float4*)&inp_s[tid*4] = ((const float4*)xg)[(bat*Tq + t + 1)*16 + tid];
      __syncthreads();
    }
  }
  else {
    // ---- mem WG: island `bat` — heads, softmax, memory update, r, out ----
    float* mem_s  = (float*)smem;               // 128 x 44
    float* h_s    = (float*)(smem + 22528);     // 512
    float* hred_s = (float*)(smem + 24576);     // 128 x 4
    float* key_s  = (float*)(smem + 26624);     // 40
    float* e_s    = (float*)(smem + 26784);     // 40
    float* a_s    = (float*)(smem + 26944);     // 40
    float* w_s    = (float*)(smem + 27104);     // 128
    float* rred_s = (float*)(smem + 27616);     // 40 x 9
    float* ored_s = (float*)(smem + 29056);     // 64 x 9

    #pragma unroll
    for (int q = 0; q < 10; ++q){
      const int e = q*512 + tid;
      const int n = e / 40, m = e - n*40;
      mem_s[n*44 + m] = mem0g[bat*(Nq*Mq) + e];
    }
    const int o  = tid & 127;
    const int kc = tid >> 7;
    const float* wrow = (o < 40) ? (Wk + o*Hq)
                      : (o < 80) ? (We + (o-40)*Hq)
                      : (o < 120) ? (Wa + (o-80)*Hq)
                      : (o == 120) ? Wb : nullptr;
    float4 wv2[32];
    if (wrow){
      #pragma unroll
      for (int kk = 0; kk < 32; ++kk)
        wv2[kk] = *(const float4*)&wrow[kc*128 + kk*4];
    } else {
      #pragma unroll
      for (int kk = 0; kk < 32; ++kk) wv2[kk] = make_float4(0.f,0.f,0.f,0.f);
    }
    float4 wfc[16];
    {
      const int o2 = tid & 63, kc8 = tid >> 6;
      #pragma unroll
      for (int kk = 0; kk < 16; ++kk)
        wfc[kk] = *(const float4*)&Wfc[o2*Hq + kc8*64 + kk*4];
    }
    const float bfcv = bfc[tid & 63];
    float hb0 = 0.f, hb1 = 0.f;
    if (tid < 64){
      const int o0 = tid, o1 = tid + 64;
      hb0 = (o0 < 40) ? bk[o0] : be[o0-40];
      hb1 = (o1 < 80) ? be[o1-40] : (o1 < 120) ? ba[o1-80]
          : (o1 == 120) ? bbeta[0] : 0.f;
    }
    __syncthreads();

    for (int t = 0; t < Tq; ++t){
      const int p = t & 1;
      const unsigned want = (unsigned)(t + 1);
      { // acquire h(t): one dim per thread
        const int idx = (p*NISL + bat)*Hq + tid;
        h_s[tid] = waitword(&h_loc[idx], &h_sh[idx], want, mode);
      }
      __syncthreads();                               // M1
      { // heads GEMV: 1 output x 4 k-chunks per thread
        float a0 = 0.f;
        const float* hp = h_s + kc*128;
        #pragma unroll
        for (int kk = 0; kk < 32; ++kk){
          const float4 f = *(const float4*)&hp[kk*4];
          a0 += wv2[kk].x*f.x + wv2[kk].y*f.y + wv2[kk].z*f.z + wv2[kk].w*f.w;
        }
        hred_s[o*4 + kc] = a0;
      }
      __syncthreads();                               // M2
      if (tid < 64){ // wave 0: serial section, shuffle-reduced
        const int l = tid;
        const float4 p0 = *(const float4*)&hred_s[l*4];
        const float4 p1 = *(const float4*)&hred_s[(l+64)*4];
        float s0 = hb0 + p0.x + p0.y + p0.z + p0.w;
        float s1 = hb1 + p1.x + p1.y + p1.z + p1.w;
        float kv = 0.f;
        if (l < 40){ kv = tanhf(s0); key_s[l] = kv; }
        else        { e_s[l-40] = sigmf(s0); }
        if (l < 16)      e_s[l+24]  = sigmf(s1);     // o1 in [64,80)
        else if (l < 56) a_s[l-16]  = tanhf(s1);     // o1 in [80,120)
        float bval = softplusf(s1) + EPSq;           // lane 56: o1==120
        const float bet = __shfl(bval, 56);
        float ss = kv*kv;
        #pragma unroll
        for (int off = 32; off; off >>= 1) ss += __shfl_xor(ss, off);
        const float rinv = 1.f/(sqrtf(ss) + EPSq);
        float sc[2];
        #pragma unroll
        for (int half = 0; half < 2; ++half){
          const int n = l + 64*half;
          float qq = 0.f, dd = 0.f;
          const float* mrow = &mem_s[n*44];
          #pragma unroll
          for (int q = 0; q < 10; ++q){
            const float4 mv = *(const float4*)&mrow[q*4];
            const float4 kvv = *(const float4*)&key_s[q*4];
            qq += mv.x*mv.x + mv.y*mv.y + mv.z*mv.z + mv.w*mv.w;
            dd += mv.x*kvv.x + mv.y*kvv.y + mv.z*kvv.z + mv.w*kvv.w;
          }
          sc[half] = bet * dd * rinv / (sqrtf(qq) + EPSq);
        }
        // softmax without max-subtraction: |beta*sim| <= ~8.3 -> fp32-safe
        // (validated: absmax identical to max-shifted form)
        const float e0 = expf(sc[0]), e1 = expf(sc[1]);
        float sm = e0 + e1;
        #pragma unroll
        for (int off = 32; off; off >>= 1) sm += __shfl_xor(sm, off);
        const float inv = 1.f/sm;
        w_s[l] = e0*inv; w_s[l+64] = e1*inv;
      }
      __syncthreads();                               // M3
      if (tid < 320){ // fused erase/add update + read partials
        const int m = tid % 40, ng = tid / 40;
        const float ev = e_s[m], av = a_s[m];
        float part = 0.f;
        #pragma unroll
        for (int q = 0; q < 16; ++q){
          const int n = ng*16 + q, idx2 = n*44 + m;
          const float mv = mem_s[idx2];
          const float wn = w_s[n];
          const float nv = fmaf(wn, fmaf(-ev, mv, av), mv);
          mem_s[idx2] = nv;
          part = fmaf(wn, nv, part);
        }
        rred_s[m*9 + ng] = part;
      }
      __syncthreads();                               // M4
      if (tid < 40){
        float r = 0.f;
        #pragma unroll
        for (int q = 0; q < 8; ++q) r += rred_s[tid*9 + q];
        const int idx = (p*NISL + bat)*Mq + tid;
        publish(&r_loc[idx], &r_sh[idx], packtv(want, r));
      }
      { // out(t) = tanh(Wfc h + bfc): off critical path, after r publish
        const int o2 = tid & 63, kc8 = tid >> 6;
        float a0 = 0.f;
        const float* hp = h_s + kc8*64;
        #pragma unroll
        for (int kk = 0; kk < 16; ++kk){
          const float4 f = *(const float4*)&hp[kk*4];
          a0 += wfc[kk].x*f.x + wfc[kk].y*f.y + wfc[kk].z*f.z + wfc[kk].w*f.w;
        }
        ored_s[o2*9 + kc8] = a0;
      }
      __syncthreads();                               // M5
      if (tid < 64){
        float s2 = bfcv;
        const float* op = &ored_s[tid*9];
        #pragma unroll
        for (int q = 0; q < 8; ++q) s2 += op[q];
        yout[(bat*Tq + t)*OUTq + tid] = tanhf(s2);
      }
      __syncthreads();                               // M6: h_s reuse guard
    }
  }
}

extern "C" void kernel_launch(void* const* d_in, const int* in_sizes, int n_in,
                              void* d_out, int out_size, void* d_ws, size_t ws_size,
                              hipStream_t stream){
  const float* xg    = (const float*)d_in[0];
  const float* h0g   = (const float*)d_in[1];
  const float* c0g   = (const float*)d_in[2];
  const float* mem0g = (const float*)d_in[3];
  const float* read0g= (const float*)d_in[4];
  const float* Wih   = (const float*)d_in[5];
  const float* bih   = (const float*)d_in[6];
  const float* Whh   = (const float*)d_in[7];
  const float* bhh   = (const float*)d_in[8];
  const float* Wfc   = (const float*)d_in[9];
  const float* bfc   = (const float*)d_in[10];
  const float* We    = (const float*)d_in[11];
  const float* be    = (const float*)d_in[12];
  const float* Wa    = (const float*)d_in[13];
  const float* ba    = (const float*)d_in[14];
  const float* Wk    = (const float*)d_in[15];
  const float* bk    = (const float*)d_in[16];
  const float* Wb    = (const float*)d_in[17];
  const float* bbeta = (const float*)d_in[18];

  float* yout  = (float*)d_out;
  ull*   rdy   = (ull*)d_ws;                         // word 0; word 1 = magic
  ull*   h_sh  = (ull*)((char*)d_ws + 4096);         // 16384 ull
  ull*   r_sh  = (ull*)((char*)d_ws + 135168);       // 1280 ull
  ull*   h_loc = (ull*)((char*)d_ws + 147456);       // 16384 ull
  ull*   r_loc = (ull*)((char*)d_ws + 278528);       // 1280 ull
  ull*   xtab  = (ull*)((char*)d_ws + 288768);       // 224 ull
  ull*   asg   = (ull*)((char*)d_ws + 290560);       // 224 ull
  ull*   votes = (ull*)((char*)d_ws + 292352);       // 16x16 ull
  ull*   verd  = (ull*)((char*)d_ws + 294400);       // 16x16 ull
  ull*   ltest = (ull*)((char*)d_ws + 296448);       // 16x16 ull

  hipMemsetAsync(d_ws, 0, 298496, stream);           // tags=0 != any want (1..1024)
  hipLaunchKernelGGL(ntm_kernel, dim3(NWG), dim3(NT), 0, stream,
                     xg, h0g, c0g, mem0g, read0g, Wih, bih, Whh, bhh,
                     Wfc, bfc, We, be, Wa, ba, Wk, bk, Wb, bbeta,
                     yout, rdy, h_sh, r_sh, h_loc, r_loc,
                     xtab, asg, votes, verd, ltest);
}

// Round 13
// 6758.860 us; speedup vs baseline: 167.0915x; 167.0915x over previous
//
#include <hip/hip_runtime.h>
#include <math.h>

#define Bq   16
#define Tq   1024
#define OUTq 64
#define Hq   512
#define Nq   128
#define Mq   40
#define NT   512
#define NISL 16        // islands = batches
#define GWG  13        // gate WGs per island (12 x 40 dims + 1 x 32 dims)
#define IWG  14        // WGs per island (GWG + 1 mem)
#define NWG  224
#define EPSq 1e-8f
#define MAGIC 0x00C0FFEEu

typedef unsigned long long ull;

__device__ __forceinline__ float sigmf(float x){ return 1.f/(1.f + expf(-x)); }
__device__ __forceinline__ float softplusf(float x){ return (x > 20.f) ? x : log1pf(expf(x)); }

// Agent-scope atomic ops: authoritative cross-XCD path (IC coherence point).
// r12 falsified the local-L2 route for the 4th time: plain stores do not
// reliably reach a same-XCD-observable L2 state. IC-only from here.
__device__ __forceinline__ ull icld64(const ull* p){
  return __hip_atomic_load(p, __ATOMIC_RELAXED, __HIP_MEMORY_SCOPE_AGENT);
}
__device__ __forceinline__ void icst64(ull* p, ull v){
  __hip_atomic_store(p, v, __ATOMIC_RELAXED, __HIP_MEMORY_SCOPE_AGENT);
}
// IC poll load: sc0+sc1 bypasses L1 and L2 -> coherent with agent stores,
// coalescing (r4-proven via runtime handshake).
__device__ __forceinline__ ull icpoll64(const ull* p){
  ull v;
  asm volatile("global_load_dwordx2 %0, %1, off sc0 sc1\n\ts_waitcnt vmcnt(0)"
               : "=v"(v) : "v"(p) : "memory");
  return v;
}
__device__ __forceinline__ ull packtv(unsigned tag, float v){
  return ((ull)tag << 32) | (ull)__float_as_uint(v);
}
__device__ __forceinline__ float lowf(ull v){ return __uint_as_float((unsigned)v); }

// Tag-verified wait (tag+payload one atomic 8B word, tags monotone, parity-2
// slot reuse guarded by the dependency chain). `fast` enabled only after the
// runtime handshake proved sc0sc1 loads observe agent stores; bounded with an
// agent-loop tail so no configuration can hang.
__device__ __forceinline__ float waitword(const ull* sh, unsigned want, bool fast){
  if (fast){
    #pragma unroll 1
    for (int i = 0; i < 4096; ++i){
      const ull v = icpoll64(sh);
      if ((unsigned)(v >> 32) == want) return lowf(v);
      __builtin_amdgcn_s_sleep(1);
    }
  }
  #pragma unroll 1
  for (;;){
    const ull v = icld64(sh);
    if ((unsigned)(v >> 32) == want) return lowf(v);
    __builtin_amdgcn_s_sleep(1);
  }
}

__device__ __forceinline__ int ready_and_handshake(ull* rdy, ull* magic, int blk){
  __hip_atomic_fetch_add(rdy, 1ull, __ATOMIC_RELAXED, __HIP_MEMORY_SCOPE_AGENT);
  while (icld64(rdy) < (ull)NWG) __builtin_amdgcn_s_sleep(8);
  if (blk == 0) icst64(magic, ((ull)MAGIC << 32) | 1ull);
  #pragma unroll 1
  for (int i = 0; i < 4000; ++i){
    if ((unsigned)(icpoll64(magic) >> 32) == MAGIC) return 1;
    __builtin_amdgcn_s_sleep(2);
  }
  return 0;
}

// r13 = r4 + heads offload, transport fixed. The mem WG's 121x512 heads GEMV
// streamed ~250KB/step of L2-resident weights BETWEEN the two IC hops (~1.7us
// of the 6.3us cycle). Gate WGs have their 40-dim h-slice BEFORE publishing h,
// so they compute the 121 partial dots locally (weights in +21KB LDS, padded
// row*41+m => <=2-way banks, unlike r11's 16-float stride) and publish 121
// words/WG. r6's defect was the consumer CHAINING 3-4 waitwords/thread (~3
// extra serialized RTTs) — here the mem WG polls its 3-4 words in PARALLEL
// round-robin. No hop added, no hop removed: the 1.7us stream just disappears.
extern "C" __global__ void __launch_bounds__(NT, 1)
ntm_kernel(const float* __restrict__ xg,  const float* __restrict__ h0g,
           const float* __restrict__ c0g, const float* __restrict__ mem0g,
           const float* __restrict__ read0g,
           const float* __restrict__ Wih, const float* __restrict__ bih,
           const float* __restrict__ Whh, const float* __restrict__ bhh,
           const float* __restrict__ Wfc, const float* __restrict__ bfc,
           const float* __restrict__ We,  const float* __restrict__ be,
           const float* __restrict__ Wa,  const float* __restrict__ ba,
           const float* __restrict__ Wk,  const float* __restrict__ bk,
           const float* __restrict__ Wb,  const float* __restrict__ bbeta,
           float* __restrict__ yout, ull* __restrict__ rdy,
           ull* __restrict__ h_sh, ull* __restrict__ r_sh,
           ull* __restrict__ hp_sh)
{
  const int blk = blockIdx.x;
  const int tid = threadIdx.x;
  const int x   = blk & 7;
  const int j   = blk >> 3;
  const int bat = (j < IWG) ? x : (x + 8);
  const int slot= (j < IWG) ? j : (j - IWG);
  __shared__ __align__(16) char smem[62464];
  __shared__ int s_fast;
  ull* magic = rdy + 1;

  if (slot < GWG){
    // ---- gate WG: island `bat`, h-dims [d0, d0+nd) + 121 head partials ----
    float* inp_s  = (float*)smem;               // 640 f: x[0,64) h[64,576)
    float* red_s  = (float*)(smem + 2560);      // 160 x 17
    float* rw_s   = (float*)(smem + 13440);     // 160 x 41 (r-slice weights)
    float* hw_s   = (float*)(smem + 39680);     // 128 x 41 head-weight slice
    float* r_s    = (float*)(smem + 60672);     // 40
    float* gate_s = (float*)(smem + 60832);     // 160
    float* c_s    = (float*)(smem + 61472);     // 40
    float* bias_s = (float*)(smem + 61632);     // 160
    float* hloc_s = (float*)(smem + 62272);     // 40 (own h-slice)

    const int kseg  = tid & 15;       // 36-float k-slice of 576 (x|h)
    const int rslot = tid >> 4;       // 32 row-slots x 5 rows (padded)
    const int nd    = (slot < 12) ? 40 : 32;
    const int d0    = slot * 40;
    const int rowsR = 4 * nd;         // 160 or 128 real rows
    const int ncol  = nd >> 2;        // 10 or 8 head-cols per quad lane

    float4 w4[5][9];
    #pragma unroll
    for (int rr = 0; rr < 5; ++rr){
      const int row = rslot*5 + rr;
      if (row < rowsR){
        const int gate = row / nd, ld = row - gate*nd;
        const int grow = gate*Hq + d0 + ld;
        #pragma unroll
        for (int kk = 0; kk < 9; ++kk){
          float v[4];
          #pragma unroll
          for (int c4 = 0; c4 < 4; ++c4){
            const int k = kseg*36 + kk*4 + c4;
            v[c4] = (k < 64) ? Wih[grow*104 + k] : Whh[grow*512 + (k - 64)];
          }
          w4[rr][kk] = make_float4(v[0], v[1], v[2], v[3]);
        }
      } else {
        #pragma unroll
        for (int kk = 0; kk < 9; ++kk) w4[rr][kk] = make_float4(0.f,0.f,0.f,0.f);
      }
    }
    if (tid < rowsR){
      const int gate = tid / nd, ld = tid - gate*nd;
      const int grow = gate*Hq + d0 + ld;
      bias_s[tid] = bih[grow] + bhh[grow];
    }
    for (int i = tid; i < rowsR*40; i += NT){
      const int row = i / 40, m = i - row*40;
      const int gate = row / nd, ld = row - gate*nd;
      const int grow = gate*Hq + d0 + ld;
      rw_s[row*41 + m] = Wih[grow*104 + 64 + m];
    }
    // head-weight slice: rows 0..120 (k|e|a|beta), cols d0..d0+nd-1, pad 41
    for (int i = tid; i < 128*41; i += NT){
      const int r = i / 41, m = i - r*41;
      float v = 0.f;
      if (r < 121 && m < nd){
        v = (r < 40) ? Wk[r*Hq + d0 + m]
          : (r < 80) ? We[(r-40)*Hq + d0 + m]
          : (r < 120) ? Wa[(r-80)*Hq + d0 + m] : Wb[d0 + m];
      }
      hw_s[i] = v;
    }
    if (tid < nd) c_s[tid] = c0g[bat*Hq + d0 + tid];
    if (tid < 40) hloc_s[tid] = 0.f;
    if (tid < 16)
      *(float4*)&inp_s[tid*4] = ((const float4*)xg)[(bat*Tq + 0)*16 + tid];
    if (tid < 128)
      *(float4*)&inp_s[64 + tid*4] = ((const float4*)h0g)[bat*128 + tid];
    __syncthreads();
    if (tid == 0) s_fast = ready_and_handshake(rdy, magic, blk);
    __syncthreads();
    const bool fast = (s_fast != 0);

    for (int t = 0; t < Tq; ++t){
      const int p = t & 1, pm = (t - 1) & 1;
      // main GEMV over x+h (576) — overlaps the island's mem phase
      float acc[5] = {0.f,0.f,0.f,0.f,0.f};
      {
        const float* bp = inp_s + kseg*36;
        #pragma unroll
        for (int kk = 0; kk < 9; ++kk){
          const float4 f = *(const float4*)&bp[kk*4];
          #pragma unroll
          for (int rr = 0; rr < 5; ++rr)
            acc[rr] += w4[rr][kk].x*f.x + w4[rr][kk].y*f.y
                     + w4[rr][kk].z*f.z + w4[rr][kk].w*f.w;
        }
      }
      #pragma unroll
      for (int rr = 0; rr < 5; ++rr)
        red_s[(rslot*5 + rr)*17 + kseg] = acc[rr];
      // r(t-1): island hop (t=0: pristine input)
      if (t == 0){
        if (tid < 40) r_s[tid] = read0g[bat*Mq + tid];
      } else if (tid < 40){
        const int idx = (pm*NISL + bat)*Mq + tid;
        r_s[tid] = waitword(&r_sh[idx], (unsigned)t, fast);
      }
      __syncthreads();                 // S1
      if (tid < rowsR){
        float s2 = bias_s[tid];
        const float* rp = &red_s[tid*17];
        #pragma unroll
        for (int q = 0; q < 16; ++q) s2 += rp[q];
        const float* rwp = &rw_s[tid*41];
        #pragma unroll
        for (int m = 0; m < 40; ++m) s2 += rwp[m]*r_s[m];
        gate_s[tid] = s2;
      }
      __syncthreads();                 // S2
      if (tid < nd){
        const float gi = gate_s[tid];
        const float gf = gate_s[nd + tid];
        const float gc = gate_s[2*nd + tid];
        const float go = gate_s[3*nd + tid];
        const float iv = sigmf(gi), fv = sigmf(gf), gv = tanhf(gc), ov = sigmf(go);
        const float cn = fv*c_s[tid] + iv*gv;
        const float hn = ov*tanhf(cn);
        c_s[tid] = cn;
        hloc_s[tid] = hn;              // own slice for the head partials
        const int idx = (p*NISL + bat)*Hq + d0 + tid;
        icst64(&h_sh[idx], packtv((unsigned)(t+1), hn));
        if (t == Tq - 1){
          yout[Bq*Tq*OUTq + bat*Hq + d0 + tid] = hn;             // final h
          yout[Bq*Tq*OUTq + Bq*Hq + bat*Hq + d0 + tid] = cn;     // final c
        }
      }
      __syncthreads();                 // S2b: hloc_s visible
      { // head partials tag t+1: row = tid>>2 (121 valid), quad covers ncol
        const int row = tid >> 2, q = tid & 3;
        if (row < 121){
          float ps = 0.f;
          const float* wp  = &hw_s[row*41 + q*ncol];
          const float* hp2 = &hloc_s[q*ncol];
          #pragma unroll
          for (int c = 0; c < 10; ++c)
            if (c < ncol) ps = fmaf(wp[c], hp2[c], ps);
          ps += __shfl_xor(ps, 1);
          ps += __shfl_xor(ps, 2);
          if (q == 0)
            icst64(&hp_sh[((p*NISL + bat)*GWG + slot)*128 + row],
                   packtv((unsigned)(t+1), ps));
        }
      }
      // stage full h(t+1) for next GEMV: one dim per thread, island hop
      {
        const int idx = (p*NISL + bat)*Hq + tid;
        inp_s[64 + tid] = waitword(&h_sh[idx], (unsigned)(t+1), fast);
      }
      if (t + 1 < Tq && tid < 16)
        *(float4*)&inp_s[tid*4] = ((const float4*)xg)[(bat*Tq + t + 1)*16 + tid];
      __syncthreads();                 // S3
    }
  }
  else {
    // ---- mem WG: island `bat` — partial wait, softmax, update, r, out ----
    float* mem_s  = (float*)smem;               // 128 x 44
    float* h_s    = (float*)(smem + 22528);     // 512
    float* hred_s = (float*)(smem + 24576);     // 128 x 4 (group sums)
    float* key_s  = (float*)(smem + 26624);     // 40
    float* e_s    = (float*)(smem + 26784);     // 40
    float* a_s    = (float*)(smem + 26944);     // 40
    float* w_s    = (float*)(smem + 27104);     // 128
    float* rred_s = (float*)(smem + 27616);     // 40 x 9
    float* ored_s = (float*)(smem + 29056);     // 64 x 9

    #pragma unroll
    for (int q = 0; q < 10; ++q){
      const int e = q*512 + tid;
      const int n = e / 40, m = e - n*40;
      mem_s[n*44 + m] = mem0g[bat*(Nq*Mq) + e];
    }
    float4 wfc[16];
    {
      const int o2 = tid & 63, kc8 = tid >> 6;
      #pragma unroll
      for (int kk = 0; kk < 16; ++kk)
        wfc[kk] = *(const float4*)&Wfc[o2*Hq + kc8*64 + kk*4];
    }
    const float bfcv = bfc[tid & 63];
    float hb0 = 0.f, hb1 = 0.f;
    if (tid < 64){
      const int o0 = tid, o1 = tid + 64;
      hb0 = (o0 < 40) ? bk[o0] : be[o0-40];
      hb1 = (o1 < 80) ? be[o1-40] : (o1 < 120) ? ba[o1-80]
          : (o1 == 120) ? bbeta[0] : 0.f;
    }
    __syncthreads();
    if (tid == 0) s_fast = ready_and_handshake(rdy, magic, blk);
    __syncthreads();
    const bool fast = (s_fast != 0);

    for (int t = 0; t < Tq; ++t){
      const int p = t & 1;
      const unsigned want = (unsigned)(t + 1);
      { // acquire 13x121 head partials: PARALLEL round-robin (r6 fix —
        // never chain waits; poll all 3-4 owned words each pass)
        const int r = tid & 127, g = tid >> 7;   // row, slot-group
        float s = 0.f;
        if (r < 121){
          const int scnt = (g == 0) ? 4 : 3;     // slots g, g+4, g+8[, g+12]
          const ull* base = &hp_sh[(p*NISL + bat)*GWG*128];
          unsigned pend = (1u << scnt) - 1u;
          float ac[4] = {0.f, 0.f, 0.f, 0.f};
          int iters = 0;
          #pragma unroll 1
          while (pend){
            #pragma unroll
            for (int k = 0; k < 4; ++k){
              if ((pend >> k) & 1){
                const ull* wp = &base[(g + 4*k)*128 + r];
                const ull v = (fast && iters < (1 << 16)) ? icpoll64(wp)
                                                          : icld64(wp);
                if ((unsigned)(v >> 32) == want){
                  ac[k] = lowf(v);
                  pend &= ~(1u << k);
                }
              }
            }
            if (pend){ __builtin_amdgcn_s_sleep(1); ++iters; }
          }
          s = ac[0] + ac[1] + ac[2] + ac[3];
        }
        hred_s[r*4 + g] = s;
      }
      __syncthreads();                               // M2
      if (tid < 64){ // wave 0: serial section, shuffle-reduced
        const int l = tid;
        const float4 p0 = *(const float4*)&hred_s[l*4];
        const float4 p1 = *(const float4*)&hred_s[(l+64)*4];
        float s0 = hb0 + p0.x + p0.y + p0.z + p0.w;
        float s1 = hb1 + p1.x + p1.y + p1.z + p1.w;
        float kv = 0.f;
        if (l < 40){ kv = tanhf(s0); key_s[l] = kv; }
        else        { e_s[l-40] = sigmf(s0); }
        if (l < 16)      e_s[l+24]  = sigmf(s1);     // rows 64..79
        else if (l < 56) a_s[l-16]  = tanhf(s1);     // rows 80..119
        float bval = softplusf(s1) + EPSq;           // lane 56: row 120
        const float bet = __shfl(bval, 56);
        float ss = kv*kv;
        #pragma unroll
        for (int off = 32; off; off >>= 1) ss += __shfl_xor(ss, off);
        const float rinv = 1.f/(sqrtf(ss) + EPSq);
        float sc[2];
        #pragma unroll
        for (int half = 0; half < 2; ++half){
          const int n = l + 64*half;
          float qq = 0.f, dd = 0.f;
          const float* mrow = &mem_s[n*44];
          #pragma unroll
          for (int q = 0; q < 10; ++q){
            const float4 mv = *(const float4*)&mrow[q*4];
            const float4 kvv = *(const float4*)&key_s[q*4];
            qq += mv.x*mv.x + mv.y*mv.y + mv.z*mv.z + mv.w*mv.w;
            dd += mv.x*kvv.x + mv.y*kvv.y + mv.z*kvv.z + mv.w*kvv.w;
          }
          sc[half] = bet * dd * rinv / (sqrtf(qq) + EPSq);
        }
        // softmax without max-subtraction: |beta*sim| <= ~8.3 -> fp32-safe
        // (validated: absmax identical to max-shifted form)
        const float e0 = expf(sc[0]), e1 = expf(sc[1]);
        float sm = e0 + e1;
        #pragma unroll
        for (int off = 32; off; off >>= 1) sm += __shfl_xor(sm, off);
        const float inv = 1.f/sm;
        w_s[l] = e0*inv; w_s[l+64] = e1*inv;
      }
      __syncthreads();                               // M3
      if (tid < 320){ // fused erase/add update + read partials
        const int m = tid % 40, ng = tid / 40;
        const float ev = e_s[m], av = a_s[m];
        float part = 0.f;
        #pragma unroll
        for (int q = 0; q < 16; ++q){
          const int n = ng*16 + q, idx2 = n*44 + m;
          const float mv = mem_s[idx2];
          const float wn = w_s[n];
          const float nv = fmaf(wn, fmaf(-ev, mv, av), mv);
          mem_s[idx2] = nv;
          part = fmaf(wn, nv, part);
        }
        rred_s[m*9 + ng] = part;
      }
      __syncthreads();                               // M4
      if (tid < 40){
        float r = 0.f;
        #pragma unroll
        for (int q = 0; q < 8; ++q) r += rred_s[tid*9 + q];
        const int idx = (p*NISL + bat)*Mq + tid;
        icst64(&r_sh[idx], packtv(want, r));
      }
      { // h(t+1) for out-GEMV: published long ago -> near-zero wait, off-chain
        const int idx = (p*NISL + bat)*Hq + tid;
        h_s[tid] = waitword(&h_sh[idx], want, fast);
      }
      __syncthreads();                               // M5a
      { // out(t) = tanh(Wfc h + bfc): off critical path
        const int o2 = tid & 63, kc8 = tid >> 6;
        float a0 = 0.f;
        const float* hp = h_s + kc8*64;
        #pragma unroll
        for (int kk = 0; kk < 16; ++kk){
          const float4 f = *(const float4*)&hp[kk*4];
          a0 += wfc[kk].x*f.x + wfc[kk].y*f.y + wfc[kk].z*f.z + wfc[kk].w*f.w;
        }
        ored_s[o2*9 + kc8] = a0;
      }
      __syncthreads();                               // M5b
      if (tid < 64){
        float s2 = bfcv;
        const float* op = &ored_s[tid*9];
        #pragma unroll
        for (int q = 0; q < 8; ++q) s2 += op[q];
        yout[(bat*Tq + t)*OUTq + tid] = tanhf(s2);
      }
      __syncthreads();                               // M6: h_s/hred reuse guard
    }
  }
}

extern "C" void kernel_launch(void* const* d_in, const int* in_sizes, int n_in,
                              void* d_out, int out_size, void* d_ws, size_t ws_size,
                              hipStream_t stream){
  const float* xg    = (const float*)d_in[0];
  const float* h0g   = (const float*)d_in[1];
  const float* c0g   = (const float*)d_in[2];
  const float* mem0g = (const float*)d_in[3];
  const float* read0g= (const float*)d_in[4];
  const float* Wih   = (const float*)d_in[5];
  const float* bih   = (const float*)d_in[6];
  const float* Whh   = (const float*)d_in[7];
  const float* bhh   = (const float*)d_in[8];
  const float* Wfc   = (const float*)d_in[9];
  const float* bfc   = (const float*)d_in[10];
  const float* We    = (const float*)d_in[11];
  const float* be    = (const float*)d_in[12];
  const float* Wa    = (const float*)d_in[13];
  const float* ba    = (const float*)d_in[14];
  const float* Wk    = (const float*)d_in[15];
  const float* bk    = (const float*)d_in[16];
  const float* Wb    = (const float*)d_in[17];
  const float* bbeta = (const float*)d_in[18];

  float* yout  = (float*)d_out;
  ull*   rdy   = (ull*)d_ws;                         // word 0; word 1 = magic
  ull*   h_sh  = (ull*)((char*)d_ws + 4096);         // 2x16x512 = 16384 ull
  ull*   r_sh  = (ull*)((char*)d_ws + 135168);       // 2x16x40 = 1280 ull
  ull*   hp_sh = (ull*)((char*)d_ws + 147456);       // 2x16x13x128 = 53248 ull

  hipMemsetAsync(d_ws, 0, 573440, stream);           // tags=0 != any want (1..1024)
  hipLaunchKernelGGL(ntm_kernel, dim3(NWG), dim3(NT), 0, stream,
                     xg, h0g, c0g, mem0g, read0g, Wih, bih, Whh, bhh,
                     Wfc, bfc, We, be, Wa, ba, Wk, bk, Wb, bbeta,
                     yout, rdy, h_sh, r_sh, hp_sh);
}